// Round 8
// baseline (130.185 us; speedup 1.0000x reference)
//
#include <hip/hip_runtime.h>
#include <math.h>

constexpr int cB = 8, cN = 1600, cT = 64, cH = 32, cHEADS = 4, cHOR = 12;
constexpr int cROWS = cB * cN;      // 12800
constexpr int NB = 400;             // blocks
constexpr int RPB = 32;             // rows per block
constexpr int BPB = 50;             // blocks per batch (1600/32)

typedef __attribute__((ext_vector_type(8))) short short8;
typedef __attribute__((ext_vector_type(4))) float f32x4;

__device__ __forceinline__ float sigmoidf_(float x) { return 1.0f / (1.0f + __expf(-x)); }
__device__ __forceinline__ float tanhf_(float x) {
    float xc = fminf(fmaxf(x, -15.0f), 15.0f);
    float e = __expf(-2.0f * xc);
    return (1.0f - e) / (1.0f + e);
}
__device__ __forceinline__ float elu1_(float x) { return (x > 0.0f) ? (x + 1.0f) : __expf(x); }
__device__ __forceinline__ short f2bf(float f) {   // RNE fp32->bf16
    unsigned u = __float_as_uint(f);
    u = (u + 0x7fffu + ((u >> 16) & 1u)) >> 16;
    return (short)u;
}

// LDS map (bytes):
//   [0, 66048)  : wbt bf16 [32][1032]            (phase A)  -- aliased after MFMA by:
//       Wq[96][33] bq[96] Wo[32][33] bo[32] qe[32][33] ske[32][33] svv[32][33]
//       skv[256] sB[32][36] sC[32][36]   (40320 B total)
//   [66048, 74368) : y1s [32][65] f32            (phase A)  -- aliased by sfeat[32][36]
#define LDS_BYTES 74368

__global__ __launch_bounds__(256, 2) void mono(
    const float* __restrict__ x,
    const float* __restrict__ dw_w, const float* __restrict__ dw_b,
    const float* __restrict__ bn1_g, const float* __restrict__ bn1_b,
    const float* __restrict__ bn1_m, const float* __restrict__ bn1_v,
    const float* __restrict__ pw_w, const float* __restrict__ pw_b,
    const float* __restrict__ bn2_g, const float* __restrict__ bn2_b,
    const float* __restrict__ bn2_m, const float* __restrict__ bn2_v,
    const float* __restrict__ fp_w, const float* __restrict__ fp_b,
    const float* __restrict__ lo_w, const float* __restrict__ lo_b,
    const float* __restrict__ hi_w, const float* __restrict__ hi_b,
    const float* __restrict__ olo_w, const float* __restrict__ olo_b,
    const float* __restrict__ ohi_w, const float* __restrict__ ohi_b,
    const float* __restrict__ hp_w, const float* __restrict__ hp_b,
    const float* __restrict__ gru_wih, const float* __restrict__ gru_whh,
    const float* __restrict__ gru_bih, const float* __restrict__ gru_bhh,
    const float* __restrict__ op_w, const float* __restrict__ op_b,
    const float* __restrict__ log_decay,
    const float* __restrict__ rg1_w, const float* __restrict__ rg1_b,
    const float* __restrict__ rg2_w, const float* __restrict__ rg2_b,
    const float* __restrict__ log_reg,
    float* __restrict__ pkv, unsigned* __restrict__ cnt,
    float* __restrict__ out)
{
    __shared__ __align__(16) unsigned char smem_[LDS_BYTES];
    short* wbt  = (short*)smem_;                    // [32][1032]
    float* y1s  = (float*)(smem_ + 66048);          // [32][65]
    float* sfeat = y1s;                             // [32][36] alias
    float* Wq  = (float*)smem_;                     // [96][33]
    float* bq  = Wq + 3168;                         // 96
    float* Wo  = bq + 96;                           // [32][33]
    float* bo  = Wo + 1056;                         // 32
    float* qe  = bo + 32;                           // [32][33]
    float* ske = qe + 1056;                         // [32][33]
    float* svv = ske + 1056;                        // [32][33]
    float* skv = svv + 1056;                        // 256
    float* sB  = skv + 256;                         // [32][36]
    float* sC  = sB + 1152;                         // [32][36]

    const int tid = threadIdx.x;
    const int bk = blockIdx.x;
    const int r0 = bk * RPB;
    const int b = __builtin_amdgcn_readfirstlane(r0 / cN);  // uniform (32 | 1600)
    const int n0 = r0 - b * cN;

    // ---------- P0: stage fp_w -> bf16 LDS (padded 1032) + y1 conv ----------
    #pragma unroll 4
    for (int q = 0; q < 32; ++q) {
        const float4 v = *(const float4*)(fp_w + (size_t)q * 1024 + tid * 4);
        short* d = wbt + q * 1032 + tid * 4;
        d[0] = f2bf(v.x); d[1] = f2bf(v.y); d[2] = f2bf(v.z); d[3] = f2bf(v.w);
    }
    {
        const float inv1 = bn1_g[0] * rsqrtf(bn1_v[0] + 1e-5f);
        const float A = inv1;
        const float C = (dw_b[0] - bn1_m[0]) * inv1 + bn1_b[0];
        const float w0 = dw_w[0], w1 = dw_w[1], w2 = dw_w[2];
        const int rr = tid & 31;
        const int t0 = (tid >> 5) * 8;
        const float* xp = x + (size_t)b * cT * cN + (n0 + rr);
        float xv[10];
        #pragma unroll
        for (int q = 0; q < 10; ++q) {
            const int t = t0 - 1 + q;
            xv[q] = (t >= 0 && t < cT) ? xp[(size_t)t * cN] : 0.0f;
        }
        #pragma unroll
        for (int q = 0; q < 8; ++q) {
            const float s = w0 * xv[q] + w1 * xv[q + 1] + w2 * xv[q + 2];
            y1s[rr * 65 + t0 + q] = fmaxf(0.0f, fmaf(s, A, C));
        }
    }
    __syncthreads();

    // ---------- P1a: MFMA feat GEMM. wave = (tile, half) ----------
    const int w    = tid >> 6;       // 0..3
    const int l    = tid & 63;
    const int tile = w >> 1;         // row-tile 0..1
    const int half = w & 1;          // K-half 0..1
    const int off  = (l >> 4) * 8;

    float a2r[8], c2r[8];
    #pragma unroll
    for (int cc = 0; cc < 8; ++cc) {
        const int c = half * 8 + cc;
        const float inv2 = bn2_g[c] * rsqrtf(bn2_v[c] + 1e-5f);
        a2r[cc] = pw_w[c] * inv2;
        c2r[cc] = (pw_b[c] - bn2_m[c]) * inv2 + bn2_b[c];
    }
    float y1r[16];
    {
        const int rl = tile * 16 + (l & 15);
        #pragma unroll
        for (int p = 0; p < 8; ++p) {
            y1r[p]     = y1s[rl * 65 + off + p];
            y1r[8 + p] = y1s[rl * 65 + 32 + off + p];
        }
    }
    f32x4 acc0 = {0.f, 0.f, 0.f, 0.f};
    f32x4 acc1 = {0.f, 0.f, 0.f, 0.f};
    {
        const short* bp0 = wbt + (l & 15) * 1032 + half * 512 + off;
        const short* bp1 = bp0 + 16 * 1032;
        #pragma unroll
        for (int kk = 0; kk < 16; ++kk) {
            const float a2 = a2r[kk >> 1], c2v = c2r[kk >> 1];
            short8 af;
            #pragma unroll
            for (int i = 0; i < 8; ++i) {
                const float y2 = fmaxf(0.0f, fmaf(a2, y1r[(kk & 1) * 8 + i], c2v));
                af[i] = f2bf(y2);
            }
            const short8 bf0 = *(const short8*)(bp0 + kk * 32);
            const short8 bf1 = *(const short8*)(bp1 + kk * 32);
            acc0 = __builtin_amdgcn_mfma_f32_16x16x32_bf16(af, bf0, acc0, 0, 0, 0);
            acc1 = __builtin_amdgcn_mfma_f32_16x16x32_bf16(af, bf1, acc1, 0, 0, 0);
        }
    }
    __syncthreads();   // all wbt reads + y1s reads done

    // ---------- P1b: half0 writes sfeat; everyone builds Wq/Wo (alias wbt) ----------
    {
        const int col = l & 15;
        const int rb = tile * 16 + (l >> 4) * 4;
        if (half == 0) {
            const float fb0 = fp_b[col], fb1 = fp_b[16 + col];
            #pragma unroll
            for (int reg = 0; reg < 4; ++reg) {
                sfeat[(rb + reg) * 36 + col]      = acc0[reg] + fb0;
                sfeat[(rb + reg) * 36 + 16 + col] = acc1[reg] + fb1;
            }
        }
    }
    #pragma unroll
    for (int k = 0; k < 12; ++k) {           // Wq[96][32] = hi_w @ lo_w
        const int g = tid + k * 256;          // 0..3071
        const int oi = g >> 5, i = g & 31;
        float s = 0.0f;
        #pragma unroll
        for (int p = 0; p < 24; ++p) s = fmaf(hi_w[oi * 24 + p], lo_w[p * 32 + i], s);
        Wq[oi * 33 + i] = s;
    }
    #pragma unroll
    for (int k = 0; k < 4; ++k) {            // Wo[32][32] = ohi_w @ olo_w
        const int g = tid + k * 256;          // 0..1023
        const int oi = g >> 5, i = g & 31;
        float s = 0.0f;
        #pragma unroll
        for (int p = 0; p < 8; ++p) s = fmaf(ohi_w[oi * 8 + p], olo_w[p * 32 + i], s);
        Wo[oi * 33 + i] = s;
    }
    if (tid < 96) {
        float s = hi_b[tid];
        #pragma unroll
        for (int p = 0; p < 24; ++p) s = fmaf(hi_w[tid * 24 + p], lo_b[p], s);
        bq[tid] = s;
    }
    if (tid < 32) {
        float s = ohi_b[tid];
        #pragma unroll
        for (int p = 0; p < 8; ++p) s = fmaf(ohi_w[tid * 8 + p], olo_b[p], s);
        bo[tid] = s;
    }
    __syncthreads();
    if (half == 1) {
        const int col = l & 15;
        const int rb = tile * 16 + (l >> 4) * 4;
        #pragma unroll
        for (int reg = 0; reg < 4; ++reg) {
            sfeat[(rb + reg) * 36 + col]      += acc0[reg];
            sfeat[(rb + reg) * 36 + 16 + col] += acc1[reg];
        }
    }
    __syncthreads();

    // ---------- P1c: qkv (8 lanes/row) + elu + z-fold -> qe/ske/svv ----------
    const int r = tid >> 3;
    const int j = tid & 7;
    {
        float f[cH];
        #pragma unroll
        for (int i = 0; i < cH; ++i) f[i] = sfeat[r * 36 + i];

        float qv[4], kv4[4], vv4[4];
        #pragma unroll
        for (int m = 0; m < 4; ++m) {
            const int oi = m * 8 + j;
            float sq = bq[oi], sk = bq[32 + oi], sv = bq[64 + oi];
            #pragma unroll
            for (int i = 0; i < cH; ++i) {
                const float fv = f[i];
                sq = fmaf(fv, Wq[oi * 33 + i], sq);
                sk = fmaf(fv, Wq[(32 + oi) * 33 + i], sk);
                sv = fmaf(fv, Wq[(64 + oi) * 33 + i], sv);
            }
            qv[m] = elu1_(sq);
            kv4[m] = elu1_(sk);
            vv4[m] = sv;
        }
        float s0 = kv4[0], s1 = kv4[1], s2 = kv4[2], s3 = kv4[3];
        #pragma unroll
        for (int o2 = 1; o2 < 8; o2 <<= 1) {
            s0 += __shfl_xor(s0, o2, 8);
            s1 += __shfl_xor(s1, o2, 8);
            s2 += __shfl_xor(s2, o2, 8);
            s3 += __shfl_xor(s3, o2, 8);
        }
        const float z0 = 1.0f / (s0 + 1e-8f), z1 = 1.0f / (s1 + 1e-8f);
        const float z2 = 1.0f / (s2 + 1e-8f), z3 = 1.0f / (s3 + 1e-8f);
        qe[r * 33 + j]      = qv[0] * z0;
        qe[r * 33 + 8 + j]  = qv[1] * z1;
        qe[r * 33 + 16 + j] = qv[2] * z2;
        qe[r * 33 + 24 + j] = qv[3] * z3;
        #pragma unroll
        for (int m = 0; m < 4; ++m) {
            ske[r * 33 + m * 8 + j] = kv4[m];
            svv[r * 33 + m * 8 + j] = vv4[m];
        }
    }
    __syncthreads();

    // ---------- P1d: per-block kv partial -> pkv (no atomics) ----------
    {
        const int h = tid >> 6, d = (tid >> 3) & 7, e = tid & 7;
        float s = 0.0f;
        #pragma unroll
        for (int rr = 0; rr < RPB; ++rr)
            s = fmaf(ske[rr * 33 + h * 8 + d], svv[rr * 33 + h * 8 + e], s);
        pkv[(size_t)bk * 256 + tid] = s;
    }

    // ---------- grid barrier (counter pre-zeroed by memset node) ----------
    __threadfence();
    __syncthreads();
    if (tid == 0) {
        const unsigned old = atomicAdd(cnt, 1u);
        const unsigned target = (old / (unsigned)NB + 1u) * (unsigned)NB;
        while (__hip_atomic_load(cnt, __ATOMIC_ACQUIRE, __HIP_MEMORY_SCOPE_AGENT) < target)
            __builtin_amdgcn_s_sleep(8);
    }
    __syncthreads();
    __threadfence();

    // ---------- P2: reduce this batch's 50 partials -> skv ----------
    {
        const float* pp = pkv + (size_t)(b * BPB) * 256 + tid;
        float s0 = 0.f, s1 = 0.f;
        #pragma unroll 5
        for (int p = 0; p < BPB; p += 2) {
            s0 += pp[(size_t)p * 256];
            s1 += pp[(size_t)(p + 1) * 256];
        }
        skv[tid] = s0 + s1;
    }
    __syncthreads();

    // ---------- P3: att + out-proj + h0/gate + GRU + blend ----------
    const int row = r0 + r;
    const int n = n0 + r;

    float o_m[4];
    #pragma unroll
    for (int m = 0; m < 4; ++m) {
        float s = 0.0f;
        #pragma unroll
        for (int d = 0; d < 8; ++d)
            s = fmaf(qe[r * 33 + m * 8 + d], skv[m * 64 + d * 8 + j], s);
        o_m[m] = s;
    }
    #pragma unroll
    for (int m = 0; m < 4; ++m) sB[r * 36 + m * 8 + j] = o_m[m];
    __syncthreads();

    float f2_m[4];
    #pragma unroll
    for (int m = 0; m < 4; ++m) {
        const int i = m * 8 + j;
        float s = bo[i];
        #pragma unroll
        for (int q = 0; q < cH; ++q) s = fmaf(sB[r * 36 + q], Wo[i * 33 + q], s);
        f2_m[m] = sfeat[r * 36 + i] + s;
        sC[r * 36 + i] = f2_m[m];
    }
    __syncthreads();

    float h0_j = hp_b[j], g1_j = rg1_b[j];
    #pragma unroll
    for (int i = 0; i < cH; ++i) {
        const float fv = sC[r * 36 + i];
        h0_j = fmaf(fv, hp_w[j * cH + i], h0_j);
        g1_j = fmaf(fv, rg1_w[j * cH + i], g1_j);
    }
    g1_j = fmaxf(0.0f, g1_j);

    float g1f[8];
    #pragma unroll
    for (int i = 0; i < 8; ++i) g1f[i] = __shfl(g1_j, i, 8);

    float ga = rg2_b[j], gb_ = rg2_b[8 + (j & 3)];
    #pragma unroll
    for (int q = 0; q < 8; ++q) {
        ga = fmaf(g1f[q], rg2_w[j * 8 + q], ga);
        gb_ = fmaf(g1f[q], rg2_w[(8 + (j & 3)) * 8 + q], gb_);
    }
    const float gate_a = sigmoidf_(ga);
    const float gate_b = sigmoidf_(gb_);

    const float last = x[(size_t)b * cT * cN + (size_t)(cT - 1) * cN + n];

    float whh_r[8], whh_z[8], whh_n[8], opw[8];
    #pragma unroll
    for (int i = 0; i < 8; ++i) {
        whh_r[i] = gru_whh[j * 8 + i];
        whh_z[i] = gru_whh[(8 + j) * 8 + i];
        whh_n[i] = gru_whh[(16 + j) * 8 + i];
        opw[i] = op_w[i];
    }
    const float wih_r = gru_wih[j], wih_z = gru_wih[8 + j], wih_n = gru_wih[16 + j];
    const float bih_r = gru_bih[j], bih_z = gru_bih[8 + j], bih_n = gru_bih[16 + j];
    const float bhh_r = gru_bhh[j], bhh_z = gru_bhh[8 + j], bhh_n = gru_bhh[16 + j];
    const float opb = op_b[0];

    float h_full[8];
    #pragma unroll
    for (int i = 0; i < 8; ++i) h_full[i] = __shfl(h0_j, i, 8);
    float h_own = h0_j;
    float cur = last;
    float po_a = 0.0f, po_b = 0.0f;

    #pragma unroll
    for (int s = 0; s < cHOR; ++s) {
        float ghr = bhh_r, ghz = bhh_z, ghn = bhh_n;
        #pragma unroll
        for (int i = 0; i < 8; ++i) {
            ghr = fmaf(h_full[i], whh_r[i], ghr);
            ghz = fmaf(h_full[i], whh_z[i], ghz);
            ghn = fmaf(h_full[i], whh_n[i], ghn);
        }
        const float r_ = sigmoidf_(fmaf(wih_r, cur, bih_r) + ghr);
        const float zg = sigmoidf_(fmaf(wih_z, cur, bih_z) + ghz);
        const float nn = tanhf_(fmaf(wih_n, cur, bih_n) + r_ * ghn);
        const float hn = (1.0f - zg) * nn + zg * h_own;
        h_own = hn;
        #pragma unroll
        for (int i = 0; i < 8; ++i) h_full[i] = __shfl(hn, i, 8);
        float p = opb;
        #pragma unroll
        for (int i = 0; i < 8; ++i) p = fmaf(h_full[i], opw[i], p);
        po_a = (s == j) ? p : po_a;
        po_b = (s == 8 + j) ? p : po_b;
        cur = p;
    }

    const float dk = __expf(log_decay[0]);
    float* orow = out + (size_t)row * 12;
    orow[j] = gate_a * po_a + (1.0f - gate_a) * last * __expf(-dk * (float)(j + 1));
    if (j < 4)
        orow[8 + j] = gate_b * po_b + (1.0f - gate_b) * last * __expf(-dk * (float)(j + 9));

    if (bk == 0 && tid == 0)
        out[(size_t)cROWS * 12] = __expf(log_reg[0]) * (1.0f / (float)cN);
}

extern "C" void kernel_launch(void* const* d_in, const int* in_sizes, int n_in,
                              void* d_out, int out_size, void* d_ws, size_t ws_size,
                              hipStream_t stream)
{
    const float* x      = (const float*)d_in[0];
    const float* dw_w   = (const float*)d_in[1];
    const float* dw_b   = (const float*)d_in[2];
    const float* bn1_g  = (const float*)d_in[3];
    const float* bn1_b  = (const float*)d_in[4];
    const float* bn1_m  = (const float*)d_in[5];
    const float* bn1_v  = (const float*)d_in[6];
    const float* pw_w   = (const float*)d_in[7];
    const float* pw_b   = (const float*)d_in[8];
    const float* bn2_g  = (const float*)d_in[9];
    const float* bn2_b  = (const float*)d_in[10];
    const float* bn2_m  = (const float*)d_in[11];
    const float* bn2_v  = (const float*)d_in[12];
    const float* fp_w   = (const float*)d_in[13];
    const float* fp_b   = (const float*)d_in[14];
    const float* lo_w   = (const float*)d_in[15];
    const float* lo_b   = (const float*)d_in[16];
    const float* hi_w   = (const float*)d_in[17];
    const float* hi_b   = (const float*)d_in[18];
    const float* olo_w  = (const float*)d_in[19];
    const float* olo_b  = (const float*)d_in[20];
    const float* ohi_w  = (const float*)d_in[21];
    const float* ohi_b  = (const float*)d_in[22];
    // d_in[23]=u, d_in[24]=v dead (softmax row-sums == 1 -> mean|attn| == 1/N)
    const float* log_reg = (const float*)d_in[25];
    const float* hp_w   = (const float*)d_in[26];
    const float* hp_b   = (const float*)d_in[27];
    const float* gru_wih = (const float*)d_in[28];
    const float* gru_whh = (const float*)d_in[29];
    const float* gru_bih = (const float*)d_in[30];
    const float* gru_bhh = (const float*)d_in[31];
    const float* op_w   = (const float*)d_in[32];
    const float* op_b   = (const float*)d_in[33];
    const float* log_decay = (const float*)d_in[34];
    const float* rg1_w  = (const float*)d_in[35];
    const float* rg1_b  = (const float*)d_in[36];
    const float* rg2_w  = (const float*)d_in[37];
    const float* rg2_b  = (const float*)d_in[38];

    float* ws = (float*)d_ws;
    float* pkv = ws;                              // [400][256]
    unsigned* cnt = (unsigned*)(ws + NB * 256);   // barrier counter

    hipMemsetAsync(cnt, 0, sizeof(unsigned), stream);
    mono<<<NB, 256, 0, stream>>>(x, dw_w, dw_b, bn1_g, bn1_b, bn1_m, bn1_v,
                                 pw_w, pw_b, bn2_g, bn2_b, bn2_m, bn2_v,
                                 fp_w, fp_b, lo_w, lo_b, hi_w, hi_b,
                                 olo_w, olo_b, ohi_w, ohi_b,
                                 hp_w, hp_b, gru_wih, gru_whh, gru_bih, gru_bhh,
                                 op_w, op_b, log_decay,
                                 rg1_w, rg1_b, rg2_w, rg2_b, log_reg,
                                 pkv, cnt, (float*)d_out);
}

// Round 9
// 45.408 us; speedup vs baseline: 2.8670x; 2.8670x over previous
//
#include <hip/hip_runtime.h>
#include <math.h>

constexpr int cB = 8, cN = 1600, cT = 64, cH = 32, cHEADS = 4, cHOR = 12;
constexpr int cROWS = cB * cN; // 12800

typedef __attribute__((ext_vector_type(8))) short short8;
typedef __attribute__((ext_vector_type(4))) float f32x4;

__device__ __forceinline__ float sigmoidf_(float x) { return 1.0f / (1.0f + __expf(-x)); }
__device__ __forceinline__ float tanhf_(float x) {
    float xc = fminf(fmaxf(x, -15.0f), 15.0f);
    float e = __expf(-2.0f * xc);
    return (1.0f - e) / (1.0f + e);
}
__device__ __forceinline__ float elu1_(float x) { return (x > 0.0f) ? (x + 1.0f) : __expf(x); }
__device__ __forceinline__ short f2bf(float f) {   // RNE fp32->bf16
    unsigned u = __float_as_uint(f);
    u = (u + 0x7fffu + ((u >> 16) & 1u)) >> 16;
    return (short)u;
}

// k0_prep: wbt = bf16(fp_w); W_qkv_eff = hi_w@lo_w (+bias); W_out_eff = ohi_w@olo_w (+bias).
__global__ __launch_bounds__(256) void k0_prep(
    const float* __restrict__ fp_w,
    const float* __restrict__ lo_w, const float* __restrict__ lo_b,
    const float* __restrict__ hi_w, const float* __restrict__ hi_b,
    const float* __restrict__ olo_w, const float* __restrict__ olo_b,
    const float* __restrict__ ohi_w, const float* __restrict__ ohi_b,
    unsigned short* __restrict__ wbt,
    float* __restrict__ Wq, float* __restrict__ bq,
    float* __restrict__ Wo, float* __restrict__ bo)
{
    const int g = blockIdx.x * 256 + threadIdx.x;   // 0..32767
    wbt[g] = (unsigned short)f2bf(fp_w[g]);
    if (g < 3072) {          // W_qkv_eff[96][32]
        const int oi = g >> 5, i = g & 31;
        float s = 0.0f;
        #pragma unroll
        for (int p = 0; p < 24; ++p) s = fmaf(hi_w[oi * 24 + p], lo_w[p * 32 + i], s);
        Wq[g] = s;
    }
    if (g < 1024) {          // W_out_eff[32][32]
        const int i = g >> 5, q = g & 31;
        float s = 0.0f;
        #pragma unroll
        for (int p = 0; p < 8; ++p) s = fmaf(ohi_w[i * 8 + p], olo_w[p * 32 + q], s);
        Wo[g] = s;
    }
    if (g < 96) {
        float s = hi_b[g];
        #pragma unroll
        for (int p = 0; p < 24; ++p) s = fmaf(hi_w[g * 24 + p], lo_b[p], s);
        bq[g] = s;
    }
    if (g < 32) {
        float s = ohi_b[g];
        #pragma unroll
        for (int p = 0; p < 8; ++p) s = fmaf(ohi_w[g * 8 + p], olo_b[p], s);
        bo[g] = s;
    }
}

// kFeat: conv/BN/ReLU -> MFMA feat GEMM, K split over 4 waves (8 MFMA steps each,
// 16 hoistable L2 loads), LDS reduce, write feat_c (+fp_b). 16 rows/block, grid 800.
__global__ __launch_bounds__(256, 2) void kFeat(
    const float* __restrict__ x,
    const float* __restrict__ dw_w, const float* __restrict__ dw_b,
    const float* __restrict__ bn1_g, const float* __restrict__ bn1_b,
    const float* __restrict__ bn1_m, const float* __restrict__ bn1_v,
    const float* __restrict__ pw_w, const float* __restrict__ pw_b,
    const float* __restrict__ bn2_g, const float* __restrict__ bn2_b,
    const float* __restrict__ bn2_m, const float* __restrict__ bn2_v,
    const unsigned short* __restrict__ wbt, const float* __restrict__ fp_b,
    float* __restrict__ feat_c)
{
    __shared__ float y1s[16 * 65];
    __shared__ float pacc[4][512];

    const int tid = threadIdx.x;
    const int l = tid & 63;
    const int w = __builtin_amdgcn_readfirstlane(tid >> 6); // 0..3 = K-slice
    const int bk = blockIdx.x;
    const int r0 = bk * 16;
    const int b = r0 / cN;          // uniform (16 | 1600)
    const int n0 = r0 - b * cN;

    const float inv1 = bn1_g[0] * rsqrtf(bn1_v[0] + 1e-5f);
    const float A = inv1;
    const float C = (dw_b[0] - bn1_m[0]) * inv1 + bn1_b[0];
    const float w0 = dw_w[0], w1 = dw_w[1], w2 = dw_w[2];

    // y1 conv: thread = (rr = tid&15, tq = tid>>4)
    {
        const int rr = tid & 15;
        const int t0 = (tid >> 4) * 4;
        const float* xp = x + (size_t)b * cT * cN + (n0 + rr);
        float xv[6];
        #pragma unroll
        for (int q = 0; q < 6; ++q) {
            const int t = t0 - 1 + q;
            xv[q] = (t >= 0 && t < cT) ? xp[(size_t)t * cN] : 0.0f;
        }
        #pragma unroll
        for (int q = 0; q < 4; ++q) {
            const float s = w0 * xv[q] + w1 * xv[q + 1] + w2 * xv[q + 2];
            y1s[rr * 65 + t0 + q] = fmaxf(0.0f, fmaf(s, A, C));
        }
    }
    __syncthreads();

    // wave w: kk = w*8 .. w*8+8 (channels c = w*4 .. w*4+4)
    float a2r[4], c2r[4];
    #pragma unroll
    for (int cc = 0; cc < 4; ++cc) {
        const int c = w * 4 + cc;
        const float inv2 = bn2_g[c] * rsqrtf(bn2_v[c] + 1e-5f);
        a2r[cc] = pw_w[c] * inv2;
        c2r[cc] = (pw_b[c] - bn2_m[c]) * inv2 + bn2_b[c];
    }

    const int rl = l & 15;
    const int off = (l >> 4) * 8;
    float y1r[16];
    #pragma unroll
    for (int p = 0; p < 8; ++p) {
        y1r[p]     = y1s[rl * 65 + off + p];
        y1r[8 + p] = y1s[rl * 65 + 32 + off + p];
    }

    const unsigned short* b0p = wbt + (size_t)(l & 15) * 1024 + off;
    const unsigned short* b1p = wbt + (size_t)(16 + (l & 15)) * 1024 + off;

    f32x4 acc0 = {0.f, 0.f, 0.f, 0.f};
    f32x4 acc1 = {0.f, 0.f, 0.f, 0.f};

    #pragma unroll
    for (int q = 0; q < 8; ++q) {
        const int kk = w * 8 + q;               // uniform
        const float a2 = a2r[q >> 1], c2v = c2r[q >> 1];
        short8 af;
        #pragma unroll
        for (int i = 0; i < 8; ++i) {
            const float y2 = fmaxf(0.0f, fmaf(a2, y1r[(q & 1) * 8 + i], c2v));
            af[i] = f2bf(y2);
        }
        const short8 bf0 = *(const short8*)(b0p + kk * 32);
        const short8 bf1 = *(const short8*)(b1p + kk * 32);
        acc0 = __builtin_amdgcn_mfma_f32_16x16x32_bf16(af, bf0, acc0, 0, 0, 0);
        acc1 = __builtin_amdgcn_mfma_f32_16x16x32_bf16(af, bf1, acc1, 0, 0, 0);
    }

    // partials: C/D layout col=l&15, row=(l>>4)*4+reg
    {
        const int col = l & 15;
        const int rb = (l >> 4) * 4;
        #pragma unroll
        for (int reg = 0; reg < 4; ++reg) {
            pacc[w][(rb + reg) * 32 + col]      = acc0[reg];
            pacc[w][(rb + reg) * 32 + 16 + col] = acc1[reg];
        }
    }
    __syncthreads();

    #pragma unroll
    for (int o2 = 0; o2 < 2; ++o2) {
        const int o = tid + o2 * 256;          // 0..511 = rp*32+h
        const int h = o & 31;
        const float s = pacc[0][o] + pacc[1][o] + pacc[2][o] + pacc[3][o] + fp_b[h];
        feat_c[(size_t)r0 * cH + o] = s;       // coalesced
    }
}

// k2: qkv via effective Wq (staged in LDS) + elu + z folded into qe + per-block kv
// partial -> pkv (no atomics). 8 lanes/row, 32 rows/block, grid 400.
__global__ __launch_bounds__(256) void k2_qkv(
    const float* __restrict__ feat_c,
    const float* __restrict__ Wq, const float* __restrict__ bq,
    float* __restrict__ qe, float* __restrict__ pkv)
{
    __shared__ float sWq[96 * 33];
    __shared__ float sbq[96];
    __shared__ float ske[32 * 33];
    __shared__ float svv[32 * 33];

    const int tid = threadIdx.x;
    const int r = tid >> 3;
    const int j = tid & 7;
    const int bk = blockIdx.x;
    const int row = bk * 32 + r;
    const int b = __builtin_amdgcn_readfirstlane((bk * 32) / cN);

    #pragma unroll
    for (int i = 0; i < 12; ++i) {           // stage Wq coalesced
        const int g = tid + i * 256;          // 0..3071
        sWq[(g >> 5) * 33 + (g & 31)] = Wq[g];
    }
    if (tid < 96) sbq[tid] = bq[tid];
    __syncthreads();

    float f[cH];
    {
        const float4* f4 = (const float4*)(feat_c + (size_t)row * cH);
        #pragma unroll
        for (int q = 0; q < 8; ++q) {
            const float4 v = f4[q];
            f[4*q] = v.x; f[4*q+1] = v.y; f[4*q+2] = v.z; f[4*q+3] = v.w;
        }
    }

    float qv[4], kv4[4], vv4[4];
    #pragma unroll
    for (int m = 0; m < 4; ++m) {
        const int oi = m * 8 + j;
        float sq = sbq[oi], sk = sbq[32 + oi], sv = sbq[64 + oi];
        #pragma unroll
        for (int i = 0; i < cH; ++i) {
            const float fv = f[i];
            sq = fmaf(fv, sWq[oi * 33 + i], sq);
            sk = fmaf(fv, sWq[(32 + oi) * 33 + i], sk);
            sv = fmaf(fv, sWq[(64 + oi) * 33 + i], sv);
        }
        qv[m] = elu1_(sq);
        kv4[m] = elu1_(sk);
        vv4[m] = sv;
    }

    float s0 = kv4[0], s1 = kv4[1], s2 = kv4[2], s3 = kv4[3];
    #pragma unroll
    for (int o2 = 1; o2 < 8; o2 <<= 1) {
        s0 += __shfl_xor(s0, o2, 8);
        s1 += __shfl_xor(s1, o2, 8);
        s2 += __shfl_xor(s2, o2, 8);
        s3 += __shfl_xor(s3, o2, 8);
    }
    const float z0 = 1.0f / (s0 + 1e-8f), z1 = 1.0f / (s1 + 1e-8f);
    const float z2 = 1.0f / (s2 + 1e-8f), z3 = 1.0f / (s3 + 1e-8f);
    qe[(size_t)row * cH + j]      = qv[0] * z0;
    qe[(size_t)row * cH + 8 + j]  = qv[1] * z1;
    qe[(size_t)row * cH + 16 + j] = qv[2] * z2;
    qe[(size_t)row * cH + 24 + j] = qv[3] * z3;
    #pragma unroll
    for (int m = 0; m < 4; ++m) {
        ske[r * 33 + m * 8 + j] = kv4[m];
        svv[r * 33 + m * 8 + j] = vv4[m];
    }
    __syncthreads();

    {
        const int h = tid >> 6, d = (tid >> 3) & 7, e = tid & 7;
        float s = 0.0f;
        #pragma unroll
        for (int rr = 0; rr < 32; ++rr)
            s = fmaf(ske[rr * 33 + h * 8 + d], svv[rr * 33 + h * 8 + e], s);
        pkv[(size_t)bk * 256 + tid] = s;
    }
}

// kB: pkv reduce (50 partials) + att + out-proj + h0/gate + GRU + blend. grid 400 x 256.
__global__ __launch_bounds__(256) void kB(
    const float* __restrict__ x,
    const float* __restrict__ feat_c, const float* __restrict__ qe,
    const float* __restrict__ pkv,
    const float* __restrict__ Wo, const float* __restrict__ bo,
    const float* __restrict__ hp_w, const float* __restrict__ hp_b,
    const float* __restrict__ gru_wih, const float* __restrict__ gru_whh,
    const float* __restrict__ gru_bih, const float* __restrict__ gru_bhh,
    const float* __restrict__ op_w, const float* __restrict__ op_b,
    const float* __restrict__ log_decay,
    const float* __restrict__ rg1_w, const float* __restrict__ rg1_b,
    const float* __restrict__ rg2_w, const float* __restrict__ rg2_b,
    const float* __restrict__ log_reg,
    float* __restrict__ out)
{
    __shared__ float sA[32][36];
    __shared__ float sB[32][36];
    __shared__ float sC[32][36];
    __shared__ float skv[256];

    const int tid = threadIdx.x;
    const int r = tid >> 3;
    const int j = tid & 7;
    const int row = blockIdx.x * 32 + r;
    const int b = __builtin_amdgcn_readfirstlane((blockIdx.x * 32) / cN);
    const int n = row - b * cN;

    // kv reduction: thread = combo, 50 partials of this batch (coalesced rows)
    {
        const float* pp = pkv + (size_t)(b * 50) * 256 + tid;
        float s0 = 0.f, s1 = 0.f;
        #pragma unroll 5
        for (int p = 0; p < 50; p += 2) {
            s0 += pp[(size_t)p * 256];
            s1 += pp[(size_t)(p + 1) * 256];
        }
        skv[tid] = s0 + s1;
    }

    {
        const float4* q4 = (const float4*)(qe + (size_t)row * cH);
        float4 v = q4[j];
        *(float4*)&sA[r][4 * j] = v;
    }
    __syncthreads();

    float o_m[4];
    #pragma unroll
    for (int m = 0; m < 4; ++m) {
        float s = 0.0f;
        #pragma unroll
        for (int d = 0; d < 8; ++d)
            s = fmaf(sA[r][m * 8 + d], skv[m * 64 + d * 8 + j], s);
        o_m[m] = s;
    }
    #pragma unroll
    for (int m = 0; m < 4; ++m) sB[r][m * 8 + j] = o_m[m];
    __syncthreads();

    float f2_m[4];
    #pragma unroll
    for (int m = 0; m < 4; ++m) {
        const int i = m * 8 + j;
        float s = bo[i];
        const float* wrow = Wo + (size_t)i * 32;
        #pragma unroll
        for (int q = 0; q < 32; ++q) s = fmaf(sB[r][q], wrow[q], s);
        f2_m[m] = feat_c[(size_t)row * cH + i] + s;
        sC[r][i] = f2_m[m];
    }
    __syncthreads();

    float h0_j = hp_b[j], g1_j = rg1_b[j];
    #pragma unroll
    for (int i = 0; i < cH; ++i) {
        const float fv = sC[r][i];
        h0_j = fmaf(fv, hp_w[j * cH + i], h0_j);
        g1_j = fmaf(fv, rg1_w[j * cH + i], g1_j);
    }
    g1_j = fmaxf(0.0f, g1_j);

    float g1f[8];
    #pragma unroll
    for (int i = 0; i < 8; ++i) g1f[i] = __shfl(g1_j, i, 8);

    float ga = rg2_b[j], gb_ = rg2_b[8 + (j & 3)];
    #pragma unroll
    for (int q = 0; q < 8; ++q) {
        ga = fmaf(g1f[q], rg2_w[j * 8 + q], ga);
        gb_ = fmaf(g1f[q], rg2_w[(8 + (j & 3)) * 8 + q], gb_);
    }
    const float gate_a = sigmoidf_(ga);
    const float gate_b = sigmoidf_(gb_);

    const float last = x[(size_t)b * cT * cN + (size_t)(cT - 1) * cN + n];

    float whh_r[8], whh_z[8], whh_n[8], opw[8];
    #pragma unroll
    for (int i = 0; i < 8; ++i) {
        whh_r[i] = gru_whh[j * 8 + i];
        whh_z[i] = gru_whh[(8 + j) * 8 + i];
        whh_n[i] = gru_whh[(16 + j) * 8 + i];
        opw[i] = op_w[i];
    }
    const float wih_r = gru_wih[j], wih_z = gru_wih[8 + j], wih_n = gru_wih[16 + j];
    const float bih_r = gru_bih[j], bih_z = gru_bih[8 + j], bih_n = gru_bih[16 + j];
    const float bhh_r = gru_bhh[j], bhh_z = gru_bhh[8 + j], bhh_n = gru_bhh[16 + j];
    const float opb = op_b[0];

    float h_full[8];
    #pragma unroll
    for (int i = 0; i < 8; ++i) h_full[i] = __shfl(h0_j, i, 8);
    float h_own = h0_j;
    float cur = last;
    float po_a = 0.0f, po_b = 0.0f;

    #pragma unroll
    for (int s = 0; s < cHOR; ++s) {
        float ghr = bhh_r, ghz = bhh_z, ghn = bhh_n;
        #pragma unroll
        for (int i = 0; i < 8; ++i) {
            ghr = fmaf(h_full[i], whh_r[i], ghr);
            ghz = fmaf(h_full[i], whh_z[i], ghz);
            ghn = fmaf(h_full[i], whh_n[i], ghn);
        }
        const float r_ = sigmoidf_(fmaf(wih_r, cur, bih_r) + ghr);
        const float zg = sigmoidf_(fmaf(wih_z, cur, bih_z) + ghz);
        const float nn = tanhf_(fmaf(wih_n, cur, bih_n) + r_ * ghn);
        const float hn = (1.0f - zg) * nn + zg * h_own;
        h_own = hn;
        #pragma unroll
        for (int i = 0; i < 8; ++i) h_full[i] = __shfl(hn, i, 8);
        float p = opb;
        #pragma unroll
        for (int i = 0; i < 8; ++i) p = fmaf(h_full[i], opw[i], p);
        po_a = (s == j) ? p : po_a;
        po_b = (s == 8 + j) ? p : po_b;
        cur = p;
    }

    const float dk = __expf(log_decay[0]);
    float* orow = out + (size_t)row * 12;
    orow[j] = gate_a * po_a + (1.0f - gate_a) * last * __expf(-dk * (float)(j + 1));
    if (j < 4)
        orow[8 + j] = gate_b * po_b + (1.0f - gate_b) * last * __expf(-dk * (float)(j + 9));

    if (row == 0 && j == 0)
        out[(size_t)cROWS * 12] = __expf(log_reg[0]) * (1.0f / (float)cN);
}

extern "C" void kernel_launch(void* const* d_in, const int* in_sizes, int n_in,
                              void* d_out, int out_size, void* d_ws, size_t ws_size,
                              hipStream_t stream)
{
    const float* x      = (const float*)d_in[0];
    const float* dw_w   = (const float*)d_in[1];
    const float* dw_b   = (const float*)d_in[2];
    const float* bn1_g  = (const float*)d_in[3];
    const float* bn1_b  = (const float*)d_in[4];
    const float* bn1_m  = (const float*)d_in[5];
    const float* bn1_v  = (const float*)d_in[6];
    const float* pw_w   = (const float*)d_in[7];
    const float* pw_b   = (const float*)d_in[8];
    const float* bn2_g  = (const float*)d_in[9];
    const float* bn2_b  = (const float*)d_in[10];
    const float* bn2_m  = (const float*)d_in[11];
    const float* bn2_v  = (const float*)d_in[12];
    const float* fp_w   = (const float*)d_in[13];
    const float* fp_b   = (const float*)d_in[14];
    const float* lo_w   = (const float*)d_in[15];
    const float* lo_b   = (const float*)d_in[16];
    const float* hi_w   = (const float*)d_in[17];
    const float* hi_b   = (const float*)d_in[18];
    const float* olo_w  = (const float*)d_in[19];
    const float* olo_b  = (const float*)d_in[20];
    const float* ohi_w  = (const float*)d_in[21];
    const float* ohi_b  = (const float*)d_in[22];
    // d_in[23]=u, d_in[24]=v dead (softmax row-sums == 1 -> mean|attn| == 1/N)
    const float* log_reg = (const float*)d_in[25];
    const float* hp_w   = (const float*)d_in[26];
    const float* hp_b   = (const float*)d_in[27];
    const float* gru_wih = (const float*)d_in[28];
    const float* gru_whh = (const float*)d_in[29];
    const float* gru_bih = (const float*)d_in[30];
    const float* gru_bhh = (const float*)d_in[31];
    const float* op_w   = (const float*)d_in[32];
    const float* op_b   = (const float*)d_in[33];
    const float* log_decay = (const float*)d_in[34];
    const float* rg1_w  = (const float*)d_in[35];
    const float* rg1_b  = (const float*)d_in[36];
    const float* rg2_w  = (const float*)d_in[37];
    const float* rg2_b  = (const float*)d_in[38];

    float* ws = (float*)d_ws;
    unsigned short* wbt = (unsigned short*)ws;     // 32768 bf16 = 16384 float slots
    float* Wq     = ws + 16384;                    // 3072
    float* bq     = Wq + 3072;                     // 128 (96 used)
    float* Wo     = bq + 128;                      // 1024
    float* bo     = Wo + 1024;                     // 64 (32 used)
    float* qe     = bo + 64;                       // 409600 (z pre-folded)
    float* feat_c = qe + 409600;                   // 409600
    float* pkv    = feat_c + 409600;               // 102400 [400][256]

    k0_prep<<<128, 256, 0, stream>>>(fp_w, lo_w, lo_b, hi_w, hi_b,
                                     olo_w, olo_b, ohi_w, ohi_b,
                                     wbt, Wq, bq, Wo, bo);
    kFeat<<<800, 256, 0, stream>>>(x, dw_w, dw_b, bn1_g, bn1_b, bn1_m, bn1_v,
                                   pw_w, pw_b, bn2_g, bn2_b, bn2_m, bn2_v,
                                   wbt, fp_b, feat_c);
    k2_qkv<<<400, 256, 0, stream>>>(feat_c, Wq, bq, qe, pkv);
    kB<<<400, 256, 0, stream>>>(x, feat_c, qe, pkv,
                                Wo, bo,
                                hp_w, hp_b, gru_wih, gru_whh, gru_bih, gru_bhh,
                                op_w, op_b, log_decay,
                                rg1_w, rg1_b, rg2_w, rg2_b, log_reg,
                                (float*)d_out);
}